// Round 5
// baseline (410.716 us; speedup 1.0000x reference)
//
#include <hip/hip_runtime.h>
#include <hip/hip_bf16.h>
#include <stdint.h>

typedef __bf16 bf16_t;
typedef __bf16 bf16x8 __attribute__((ext_vector_type(8)));
typedef __bf16 bf16x4 __attribute__((ext_vector_type(4)));
typedef float f32x4 __attribute__((ext_vector_type(4)));

// Shapes: B=4 Ng=8192 C=256 H=W=128 Nt=512 M=8 P=4 Ch=32
#define CEXP 0.25506807186679906f  // (1/sqrt(32)) * log2(e), folded into K

__device__ __forceinline__ float ldf(const void* p, size_t i, int isf) {
  return isf ? ((const float*)p)[i] : (float)((const bf16_t*)p)[i];
}

// per-wave dtype detect on query[0:128 elems] — deterministic everywhere
__device__ __forceinline__ int detect_isf(const void* q) {
  const uint16_t* u = (const uint16_t*)q;
  const int lane = threadIdx.x & 63;
  const uint16_t v = u[2 * lane];
  const int e = (v >> 7) & 0xFF;
  const int weird = (e >= 0x86 || (v != 0 && e <= 0x65)) ? 1 : 0;
  return (__popcll(__ballot(weird)) >= 16) ? 1 : 0;
}

__device__ __forceinline__ float fexp2(float x) {
#if __has_builtin(__builtin_amdgcn_exp2f)
  return __builtin_amdgcn_exp2f(x);
#else
  return exp2f(x);
#endif
}

// pack 4 f32 -> bf16x4 via v_perm (round-half-up; p>0 finite here)
__device__ __forceinline__ bf16x4 pack4(const f32x4 s) {
  union { float f; uint32_t u; } a0, a1, a2, a3;
  a0.f = fexp2(s[0]); a1.f = fexp2(s[1]); a2.f = fexp2(s[2]); a3.f = fexp2(s[3]);
  uint2 r;
  r.x = __builtin_amdgcn_perm(a1.u + 0x8000u, a0.u + 0x8000u, 0x07060302u);
  r.y = __builtin_amdgcn_perm(a3.u + 0x8000u, a2.u + 0x8000u, 0x07060302u);
  return __builtin_bit_cast(bf16x4, r);
}

// 16x16x16 bf16 MFMA: C-layout of a 16x16 tile == B-layout of this shape.
__device__ __forceinline__ f32x4 mfma16x16x16(bf16x4 a, bf16x4 b, f32x4 c) {
#if __has_builtin(__builtin_amdgcn_mfma_f32_16x16x16_bf16)
  return __builtin_amdgcn_mfma_f32_16x16x16_bf16(a, b, c, 0, 0, 0);
#else
  typedef short s16x4 __attribute__((ext_vector_type(4)));
  return __builtin_amdgcn_mfma_f32_16x16x16bf16_1k(
      __builtin_bit_cast(s16x4, a), __builtin_bit_cast(s16x4, b), c, 0, 0, 0);
#endif
}

// async global->LDS, 16B per lane
__device__ __forceinline__ void stage16(const bf16_t* g, bf16_t* l) {
  __builtin_amdgcn_global_load_lds((const __attribute__((address_space(1))) void*)g,
                                   (__attribute__((address_space(3))) void*)l, 16, 0, 0);
}

// ====== merged prep: weights->bf16 blob | tf projection | wpad hi/lo =======
__global__ __launch_bounds__(256) void prep_all(
    const void* __restrict__ query,
    const void* in_w, const void* in_b, const void* mow, const void* mob,
    const void* outw, const void* outb,
    const void* trajp, const void* tw, const void* tb,
    const void* offs_w, const void* attw_w, const void* offs_b, const void* attw_b,
    bf16_t* __restrict__ blob, bf16_t* __restrict__ tf,
    bf16_t* __restrict__ Wph, bf16_t* __restrict__ Wpl, bf16_t* __restrict__ bp)
{
  const int isf = detect_isf(query);
  const int bid = blockIdx.x;
  if (bid < 322) {
    const int g = (bid * 256 + threadIdx.x) * 4;
    if (g >= 328960) return;
    const void* src; size_t off;
    if      (g < 196608) { src = in_w; off = g; }
    else if (g < 197376) { src = in_b; off = g - 196608; }
    else if (g < 262912) { src = mow;  off = g - 197376; }
    else if (g < 263168) { src = mob;  off = g - 262912; }
    else if (g < 328704) { src = outw; off = g - 263168; }
    else                 { src = outb; off = g - 328704; }
#pragma unroll
    for (int k = 0; k < 4; k++) blob[g + k] = (bf16_t)ldf(src, off + k, isf);
  } else if (bid < 322 + 2048) {
    const int rowb = bid - 322;
    const int c = threadIdx.x;
    const float x = ldf(trajp, rowb * 2 + 0, isf);
    const float y = ldf(trajp, rowb * 2 + 1, isf);
    const float v = x * ldf(tw, c * 2 + 0, isf) + y * ldf(tw, c * 2 + 1, isf) + ldf(tb, c, isf);
    tf[(size_t)rowb * 256 + c] = (bf16_t)v;
  } else {
    const int idx = (bid - 2370) * 256 + threadIdx.x;
    const int rowp = idx >> 8, c = idx & 255;
    float v = 0.0f;
    if (rowp < 64)      v = ldf(offs_w, rowp * 256 + c, isf);
    else if (rowp < 96) v = ldf(attw_w, (rowp - 64) * 256 + c, isf);
    const bf16_t hi = (bf16_t)v;
    Wph[idx] = hi;
    Wpl[idx] = (bf16_t)(v - (float)hi);
    if (idx < 128) {
      float bv = 0.0f;
      if (idx < 64)      bv = ldf(offs_b, idx, isf);
      else if (idx < 96) bv = ldf(attw_b, idx - 64, isf);
      bp[idx] = (bf16_t)bv;
    }
  }
}

// ============== async-staged bf16 GEMM: C = A@W^T + bias ===================
// mode 0: bf16 store; mode 3: dtype-of-query store; mode 6: K scaled + V transposed
#define TM 128
#define TN 128
#define TKK 64

__global__ __launch_bounds__(256) void gemm_async(
    const bf16_t* __restrict__ A, const bf16_t* __restrict__ W,
    const bf16_t* __restrict__ bias, void* __restrict__ Cout,
    void* __restrict__ Cout2, int Ndim, int Kdim, int mode, float kscale,
    const void* __restrict__ qdet)
{
  __shared__ __align__(16) bf16_t As[TM * TKK];
  __shared__ __align__(16) bf16_t Ws[TN * TKK];
  const int t    = threadIdx.x;
  const int lane = t & 63;
  const int w    = t >> 6;
  const int wm   = (w & 1) * 64;
  const int wn   = (w >> 1) * 64;
  const int q4   = lane >> 4;
  const int r16  = lane & 15;
  const int tm   = blockIdx.x * TM;
  const int tn   = blockIdx.y * TN;

  f32x4 acc[4][4] = {};

  for (int kt = 0; kt < Kdim; kt += TKK) {
    __syncthreads();
#pragma unroll
    for (int r = 0; r < 4; r++) {
      const int L = w * 256 + r * 64 + lane;
      const int R = L >> 3, c = (L & 7) * 8;
      stage16(A + (size_t)(tm + R) * Kdim + kt + c, As + L * 8);
      stage16(W + (size_t)(tn + R) * Kdim + kt + c, Ws + L * 8);
    }
    __syncthreads();
#pragma unroll
    for (int ks = 0; ks < TKK; ks += 32) {
      bf16x8 af[4], bfm[4];
#pragma unroll
      for (int i = 0; i < 4; i++)
        af[i] = *(const bf16x8*)(As + (wm + 16 * i + r16) * TKK + ks + q4 * 8);
#pragma unroll
      for (int j = 0; j < 4; j++)
        bfm[j] = *(const bf16x8*)(Ws + (wn + 16 * j + r16) * TKK + ks + q4 * 8);
#pragma unroll
      for (int i = 0; i < 4; i++)
#pragma unroll
        for (int j = 0; j < 4; j++)
          acc[i][j] = __builtin_amdgcn_mfma_f32_16x16x32_bf16(af[i], bfm[j], acc[i][j], 0, 0, 0);
    }
  }

  const int isf = (mode == 3) ? detect_isf(qdet) : 1;
#pragma unroll
  for (int j = 0; j < 4; j++) {
    const int col = tn + wn + 16 * j + r16;
    const float bv = (float)bias[col];
#pragma unroll
    for (int i = 0; i < 4; i++) {
      const int row0 = tm + wm + 16 * i + q4 * 4;
#pragma unroll
      for (int rr = 0; rr < 4; rr++) {
        const float v = acc[i][j][rr] + bv;
        const size_t off = (size_t)(row0 + rr) * Ndim + col;
        if (mode == 0) {
          ((bf16_t*)Cout)[off] = (bf16_t)v;
        } else if (mode == 6) {
          const int rowg = row0 + rr;
          if (col < 256) {
            ((bf16_t*)Cout)[(size_t)rowg * 256 + col] = (bf16_t)(v * kscale);
          } else {
            const int bb = rowg >> 9, tt = rowg & 511;
            const int c2 = col - 256;
            const int mm = c2 >> 5, ch = c2 & 31;
            ((bf16_t*)Cout2)[(((size_t)(bb * 8 + mm) * 32 + ch) << 9) + tt] = (bf16_t)v;
          }
        } else {
          if (isf) ((float*)Cout)[off] = v; else ((bf16_t*)Cout)[off] = (bf16_t)v;
        }
      }
    }
  }
}

// ============== VGPR-staged GEMM with dtype-flex A (Q-proj) ================
__global__ __launch_bounds__(256) void gemm_f32a(
    const void* __restrict__ Araw, const bf16_t* __restrict__ W,
    const bf16_t* __restrict__ bias, bf16_t* __restrict__ Cout,
    int Ndim, int Kdim, const void* __restrict__ qdet)
{
  __shared__ __align__(16) bf16_t As[TM * TKK];
  __shared__ __align__(16) bf16_t Ws[TN * TKK];
  const int t    = threadIdx.x;
  const int lane = t & 63;
  const int w    = t >> 6;
  const int wm   = (w & 1) * 64;
  const int wn   = (w >> 1) * 64;
  const int q4   = lane >> 4;
  const int r16  = lane & 15;
  const int tm   = blockIdx.x * TM;
  const int tn   = blockIdx.y * TN;
  const int aisf = detect_isf(qdet);

  f32x4 acc[4][4] = {};
  const int srow = t >> 1;
  const int skb  = (t & 1) * 32;

  for (int kt = 0; kt < Kdim; kt += TKK) {
    __syncthreads();
    if (aisf) {
      const float4* ga = (const float4*)((const float*)Araw + (size_t)(tm + srow) * Kdim + kt + skb);
#pragma unroll
      for (int kk = 0; kk < 8; kk++) {
        const float4 u = ga[kk];
        bf16x4 h = {(bf16_t)u.x, (bf16_t)u.y, (bf16_t)u.z, (bf16_t)u.w};
        *(bf16x4*)(As + srow * TKK + skb + kk * 4) = h;
      }
    } else {
      const uint4* ga = (const uint4*)((const bf16_t*)Araw + (size_t)(tm + srow) * Kdim + kt + skb);
      uint4* la = (uint4*)(As + srow * TKK + skb);
      la[0] = ga[0]; la[1] = ga[1]; la[2] = ga[2]; la[3] = ga[3];
    }
    {
      const uint4* gw = (const uint4*)(W + (size_t)(tn + srow) * Kdim + kt + skb);
      uint4* lw = (uint4*)(Ws + srow * TKK + skb);
      lw[0] = gw[0]; lw[1] = gw[1]; lw[2] = gw[2]; lw[3] = gw[3];
    }
    __syncthreads();
#pragma unroll
    for (int ks = 0; ks < TKK; ks += 32) {
      bf16x8 af[4], bfm[4];
#pragma unroll
      for (int i = 0; i < 4; i++)
        af[i] = *(const bf16x8*)(As + (wm + 16 * i + r16) * TKK + ks + q4 * 8);
#pragma unroll
      for (int j = 0; j < 4; j++)
        bfm[j] = *(const bf16x8*)(Ws + (wn + 16 * j + r16) * TKK + ks + q4 * 8);
#pragma unroll
      for (int i = 0; i < 4; i++)
#pragma unroll
        for (int j = 0; j < 4; j++)
          acc[i][j] = __builtin_amdgcn_mfma_f32_16x16x32_bf16(af[i], bfm[j], acc[i][j], 0, 0, 0);
    }
  }

#pragma unroll
  for (int j = 0; j < 4; j++) {
    const int col = tn + wn + 16 * j + r16;
    const float bv = (float)bias[col];
#pragma unroll
    for (int i = 0; i < 4; i++) {
      const int row0 = tm + wm + 16 * i + q4 * 4;
#pragma unroll
      for (int rr = 0; rr < 4; rr++)
        Cout[(size_t)(row0 + rr) * Ndim + col] = (bf16_t)(acc[i][j][rr] + bv);
    }
  }
}

// ==================== attention: LDS-free, per-head ========================
// K pre-scaled by CEXP. S^T = K·Q^T; p = exp2(s); lsum via ones-MFMA;
// O^T = V^T·P^T. grid (Ng/128, B*M); wave owns 32 q-rows; reg prefetch of K/V.
__global__ __launch_bounds__(256) void attn_kernel(
    const bf16_t* __restrict__ Q, const bf16_t* __restrict__ Kk,
    const bf16_t* __restrict__ Vt, bf16_t* __restrict__ ctx)
{
  const int t = threadIdx.x;
  const int lane = t & 63, w = t >> 6;
  const int q4 = lane >> 4, r16 = lane & 15;
  const int bm = blockIdx.y;
  const int b = bm >> 3, m = bm & 7;
  const int q0 = blockIdx.x * 128 + w * 32;

  bf16x8 qf[2];
#pragma unroll
  for (int qt = 0; qt < 2; qt++)
    qf[qt] = *(const bf16x8*)(Q + ((size_t)(b * 8192 + q0 + qt * 16 + r16) * 256 + m * 32 + q4 * 8));

  f32x4 acc[2][2] = {};
  f32x4 accl[2] = {};
  const bf16x4 ones = {(bf16_t)1.0f, (bf16_t)1.0f, (bf16_t)1.0f, (bf16_t)1.0f};

  const bf16_t* kbase  = Kk + (size_t)b * 512 * 256 + m * 32 + (size_t)r16 * 256 + q4 * 8;
  const bf16_t* vbase0 = Vt + (size_t)bm * 32 * 512 + ((size_t)r16 << 9) + q4 * 4;
  const bf16_t* vbase1 = vbase0 + (16 << 9);

  bf16x8 kf = *(const bf16x8*)(kbase);
  bf16x4 v0 = *(const bf16x4*)(vbase0);
  bf16x4 v1 = *(const bf16x4*)(vbase1);

  for (int k0 = 0; k0 < 512; k0 += 16) {
    const int nxt = (k0 + 16) & 511;
    const bf16x8 kf_n = *(const bf16x8*)(kbase + (size_t)nxt * 256);
    const bf16x4 v0_n = *(const bf16x4*)(vbase0 + nxt);
    const bf16x4 v1_n = *(const bf16x4*)(vbase1 + nxt);
#pragma unroll
    for (int qt = 0; qt < 2; qt++) {
      f32x4 z = {};
      const f32x4 s = __builtin_amdgcn_mfma_f32_16x16x32_bf16(kf, qf[qt], z, 0, 0, 0);
      const bf16x4 p = pack4(s);
      acc[qt][0] = mfma16x16x16(v0, p, acc[qt][0]);
      acc[qt][1] = mfma16x16x16(v1, p, acc[qt][1]);
      accl[qt]   = mfma16x16x16(ones, p, accl[qt]);
    }
    kf = kf_n; v0 = v0_n; v1 = v1_n;
  }

#pragma unroll
  for (int qt = 0; qt < 2; qt++) {
    const float inv = 1.0f / accl[qt][0];
    const size_t row = (size_t)b * 8192 + q0 + qt * 16 + r16;
    bf16x4 o0, o1;
#pragma unroll
    for (int rr = 0; rr < 4; rr++) {
      o0[rr] = (bf16_t)(acc[qt][0][rr] * inv);
      o1[rr] = (bf16_t)(acc[qt][1][rr] * inv);
    }
    *(bf16x4*)(ctx + row * 256 + m * 32 + q4 * 4)      = o0;
    *(bf16x4*)(ctx + row * 256 + m * 32 + 16 + q4 * 4) = o1;
  }
}

// ================= residual + LayerNorm -> gq hi/lo split ==================
__global__ __launch_bounds__(256) void ln_kernel(
    const bf16_t* __restrict__ y2, const void* __restrict__ query,
    const void* __restrict__ g, const void* __restrict__ beta,
    bf16_t* __restrict__ gqh, bf16_t* __restrict__ gql)
{
  const int isf = detect_isf(query);
  const int rowb = blockIdx.x * 4 + (threadIdx.x >> 6);
  const int lane = threadIdx.x & 63;
  const size_t base = (size_t)rowb * 256;
  float x[4];
  float s = 0.f;
#pragma unroll
  for (int k = 0; k < 4; k++) {
    const int c = lane + 64 * k;
    x[k] = ldf(query, base + c, isf) + (float)y2[base + c];
    s += x[k];
  }
  for (int d = 1; d < 64; d <<= 1) s += __shfl_xor(s, d, 64);
  const float mu = s * (1.0f / 256.0f);
  float vs = 0.f;
#pragma unroll
  for (int k = 0; k < 4; k++) { const float d = x[k] - mu; vs += d * d; }
  for (int d = 1; d < 64; d <<= 1) vs += __shfl_xor(vs, d, 64);
  const float rstd = rsqrtf(vs * (1.0f / 256.0f) + 1e-5f);
#pragma unroll
  for (int k = 0; k < 4; k++) {
    const int c = lane + 64 * k;
    const float gv = (x[k] - mu) * rstd * ldf(g, c, isf) + ldf(beta, c, isf);
    const bf16_t hi = (bf16_t)gv;
    gqh[base + c] = hi;
    gql[base + c] = (bf16_t)(gv - (float)hi);
  }
}

// ===== fused offs/attw GEMM: ysamp = gqh*(Wh+Wl)^T + gql*Wh^T + bias =======
__global__ __launch_bounds__(256) void gemm_offs(
    const bf16_t* __restrict__ Ahg, const bf16_t* __restrict__ Alg,
    const bf16_t* __restrict__ Whg, const bf16_t* __restrict__ Wlg,
    const bf16_t* __restrict__ bias, float* __restrict__ Cout)
{
  __shared__ __align__(16) bf16_t Ah[128 * 64];
  __shared__ __align__(16) bf16_t Al[128 * 64];
  __shared__ __align__(16) bf16_t Wh[128 * 64];
  __shared__ __align__(16) bf16_t Wl[128 * 64];
  const int t    = threadIdx.x;
  const int lane = t & 63;
  const int w    = t >> 6;
  const int wm   = (w & 1) * 64;
  const int wn   = (w >> 1) * 64;
  const int q4   = lane >> 4;
  const int r16  = lane & 15;
  const int tm   = blockIdx.x * 128;

  f32x4 acc[4][4] = {};
  const int srow = t >> 1;
  const int skb  = (t & 1) * 32;

  for (int kt = 0; kt < 256; kt += 64) {
    __syncthreads();
    {
      const uint4* g0 = (const uint4*)(Ahg + (size_t)(tm + srow) * 256 + kt + skb);
      uint4* l0 = (uint4*)(Ah + srow * 64 + skb);
      l0[0] = g0[0]; l0[1] = g0[1]; l0[2] = g0[2]; l0[3] = g0[3];
      const uint4* g1 = (const uint4*)(Alg + (size_t)(tm + srow) * 256 + kt + skb);
      uint4* l1 = (uint4*)(Al + srow * 64 + skb);
      l1[0] = g1[0]; l1[1] = g1[1]; l1[2] = g1[2]; l1[3] = g1[3];
      const uint4* g2 = (const uint4*)(Whg + (size_t)srow * 256 + kt + skb);
      uint4* l2 = (uint4*)(Wh + srow * 64 + skb);
      l2[0] = g2[0]; l2[1] = g2[1]; l2[2] = g2[2]; l2[3] = g2[3];
      const uint4* g3 = (const uint4*)(Wlg + (size_t)srow * 256 + kt + skb);
      uint4* l3 = (uint4*)(Wl + srow * 64 + skb);
      l3[0] = g3[0]; l3[1] = g3[1]; l3[2] = g3[2]; l3[3] = g3[3];
    }
    __syncthreads();
#pragma unroll
    for (int ks = 0; ks < 64; ks += 32) {
      bf16x8 ah[4], al[4], bh[4], bl[4];
#pragma unroll
      for (int i = 0; i < 4; i++) {
        ah[i] = *(const bf16x8*)(Ah + (wm + 16 * i + r16) * 64 + ks + q4 * 8);
        al[i] = *(const bf16x8*)(Al + (wm + 16 * i + r16) * 64 + ks + q4 * 8);
      }
#pragma unroll
      for (int j = 0; j < 4; j++) {
        bh[j] = *(const bf16x8*)(Wh + (wn + 16 * j + r16) * 64 + ks + q4 * 8);
        bl[j] = *(const bf16x8*)(Wl + (wn + 16 * j + r16) * 64 + ks + q4 * 8);
      }
#pragma unroll
      for (int i = 0; i < 4; i++)
#pragma unroll
        for (int j = 0; j < 4; j++) {
          f32x4 a = acc[i][j];
          a = __builtin_amdgcn_mfma_f32_16x16x32_bf16(al[i], bh[j], a, 0, 0, 0);
          a = __builtin_amdgcn_mfma_f32_16x16x32_bf16(ah[i], bl[j], a, 0, 0, 0);
          a = __builtin_amdgcn_mfma_f32_16x16x32_bf16(ah[i], bh[j], a, 0, 0, 0);
          acc[i][j] = a;
        }
    }
  }

#pragma unroll
  for (int j = 0; j < 4; j++) {
    const int col = wn + 16 * j + r16;
    const float bv = (float)bias[col];
#pragma unroll
    for (int i = 0; i < 4; i++) {
      const int row0 = tm + wm + 16 * i + q4 * 4;
#pragma unroll
      for (int rr = 0; rr < 4; rr++)
        Cout[(size_t)(row0 + rr) * 128 + col] = acc[i][j][rr] + bv;
    }
  }
}

// ============ value transpose (B,C,H,W) -> (B,M,H,W,Ch) bf16 ===============
__global__ __launch_bounds__(256) void transpose_value(
    const void* __restrict__ V, bf16_t* __restrict__ Vp, const void* __restrict__ qdet)
{
  __shared__ bf16_t tile[32][130];
  const int isf = detect_isf(qdet);
  const int bid = blockIdx.x;
  const int h = bid & 127;
  const int bm = bid >> 7;
  const int b = bm >> 3, mm = bm & 7;
  const int t = threadIdx.x;
  for (int idx = t; idx < 32 * 128; idx += 256) {
    const int ch = idx >> 7, ww = idx & 127;
    tile[ch][ww] = (bf16_t)ldf(V, (((size_t)b * 256 + mm * 32 + ch) * 128 + h) * 128 + ww, isf);
  }
  __syncthreads();
  const size_t base = ((size_t)bm * 128 + h) * 4096;
  for (int idx = t; idx < 32 * 128; idx += 256) {
    const int ww = idx >> 5, ch = idx & 31;
    Vp[base + idx] = tile[ch][ww];
  }
}

// ===================== deformable bilinear sampler =========================
__global__ __launch_bounds__(256) void sampler(
    const float* __restrict__ ys, const void* __restrict__ refp,
    const bf16_t* __restrict__ vperm, bf16_t* __restrict__ outs,
    const void* __restrict__ qdet)
{
  const int isf = detect_isf(qdet);
  const int t = threadIdx.x;
  const int qt = blockIdx.x;
  const int bm = blockIdx.y;
  const int b = bm >> 3, m = bm & 7;
  const int qq = qt * 256 + t;
  const size_t row = (size_t)b * 8192 + qq;
  const float* y = ys + row * 128;
  const float rx = ldf(refp, row * 2 + 0, isf);
  const float ry = ldf(refp, row * 2 + 1, isf);

  const float l0 = y[64 + m * 4 + 0], l1 = y[64 + m * 4 + 1];
  const float l2 = y[64 + m * 4 + 2], l3 = y[64 + m * 4 + 3];
  const float mx = fmaxf(fmaxf(l0, l1), fmaxf(l2, l3));
  const float e0 = __expf(l0 - mx), e1 = __expf(l1 - mx);
  const float e2 = __expf(l2 - mx), e3 = __expf(l3 - mx);
  const float inv = 1.0f / (e0 + e1 + e2 + e3);
  const float aw[4] = {e0 * inv, e1 * inv, e2 * inv, e3 * inv};

  float acc[32];
#pragma unroll
  for (int ch = 0; ch < 32; ch++) acc[ch] = 0.0f;

  const bf16_t* vbase = vperm + (size_t)bm * (128 * 128 * 32);

  for (int p = 0; p < 4; p++) {
    const float gx = (rx + y[m * 8 + p * 2 + 0]) * 128.0f - 0.5f;
    const float gy = (ry + y[m * 8 + p * 2 + 1]) * 128.0f - 0.5f;
    const float x0f = floorf(gx), y0f = floorf(gy);
    const int x0 = (int)x0f, y0i = (int)y0f;
    const float wx1 = gx - x0f, wx0 = 1.0f - wx1;
    const float wy1 = gy - y0f, wy0 = 1.0f - wy1;
    const float a = aw[p];
    for (int cy = 0; cy < 2; cy++) {
      const int yy = y0i + cy;
      if (yy < 0 || yy >= 128) continue;
      const float wy = cy ? wy1 : wy0;
      for (int cx = 0; cx < 2; cx++) {
        const int xx = x0 + cx;
        if (xx < 0 || xx >= 128) continue;
        const float wgt = a * wy * (cx ? wx1 : wx0);
        const bf16x8* src8 = (const bf16x8*)(vbase + ((size_t)yy * 128 + xx) * 32);
#pragma unroll
        for (int vv = 0; vv < 4; vv++) {
          const bf16x8 d = src8[vv];
#pragma unroll
          for (int e = 0; e < 8; e++) acc[vv * 8 + e] += wgt * (float)d[e];
        }
      }
    }
  }

  const size_t obase = (size_t)b * 8192;
#pragma unroll
  for (int ch = 0; ch < 32; ch++) {
    const size_t orow = obase + (size_t)(ch * 8 + m) * 32 + qt;
    outs[orow * 256 + t] = (bf16_t)acc[ch];
  }
}

// ===========================================================================
extern "C" void kernel_launch(void* const* d_in, const int* in_sizes, int n_in,
                              void* d_out, int out_size, void* d_ws, size_t ws_size,
                              hipStream_t stream) {
  const void* query = d_in[0];
  const void* value = d_in[1];
  const void* refp  = d_in[2];
  const void* trajp = d_in[3];
  const void* in_w  = d_in[4];
  const void* in_b  = d_in[5];
  const void* mow   = d_in[6];
  const void* mob   = d_in[7];
  const void* lng   = d_in[8];
  const void* lnb   = d_in[9];
  const void* tw    = d_in[10];
  const void* tb    = d_in[11];
  const void* ow    = d_in[12];
  const void* ob    = d_in[13];
  const void* aww   = d_in[14];
  const void* awb   = d_in[15];
  const void* outw  = d_in[16];
  const void* outb  = d_in[17];

  char* base = (char*)d_ws;
  float*  ysamp = (float*)(base);
  bf16_t* qout  = (bf16_t*)(base + 16777216);
  bf16_t* ctx   = (bf16_t*)(base + 33554432);
  bf16_t* y2    = (bf16_t*)(base + 50331648);
  bf16_t* tf_ws = (bf16_t*)(base + 67108864);
  bf16_t* k_ws  = (bf16_t*)(base + 68157440);
  bf16_t* vt_g  = (bf16_t*)(base + 69206016);
  bf16_t* blob  = (bf16_t*)(base + 70254592);

  bf16_t* gqh   = qout;
  bf16_t* gql   = ctx;
  bf16_t* vperm = (bf16_t*)(base + 16777216);   // 32MB, alias R1+R2
  bf16_t* outs  = y2;

  bf16_t* inw_bf  = blob;
  bf16_t* inb_bf  = blob + 196608;
  bf16_t* mow_bf  = blob + 197376;
  bf16_t* mob_bf  = blob + 262912;
  bf16_t* outw_bf = blob + 263168;
  bf16_t* outb_bf = blob + 328704;
  bf16_t* wph     = blob + 328960;
  bf16_t* wpl     = blob + 361728;
  bf16_t* bpad    = blob + 394496;

  prep_all<<<dim3(2498), dim3(256), 0, stream>>>(
      query, in_w, in_b, mow, mob, outw, outb, trajp, tw, tb,
      ow, aww, ob, awb, blob, tf_ws, wph, wpl, bpad);
  gemm_async<<<dim3(16, 4), dim3(256), 0, stream>>>(
      tf_ws, inw_bf + 65536, inb_bf + 256, (void*)k_ws, (void*)vt_g, 512, 256, 6, CEXP, query);
  gemm_f32a<<<dim3(256, 2), dim3(256), 0, stream>>>(
      query, inw_bf, inb_bf, qout, 256, 256, query);
  attn_kernel<<<dim3(64, 32), dim3(256), 0, stream>>>(qout, k_ws, vt_g, ctx);
  gemm_async<<<dim3(256, 2), dim3(256), 0, stream>>>(
      ctx, mow_bf, mob_bf, (void*)y2, nullptr, 256, 256, 0, 1.0f, query);
  ln_kernel<<<dim3(8192), dim3(256), 0, stream>>>(y2, query, lng, lnb, gqh, gql);
  gemm_offs<<<dim3(256, 1), dim3(256), 0, stream>>>(gqh, gql, wph, wpl, bpad, ysamp);
  transpose_value<<<dim3(4096), dim3(256), 0, stream>>>(value, vperm, query);
  sampler<<<dim3(32, 32), dim3(256), 0, stream>>>(ysamp, refp, vperm, outs, query);
  gemm_async<<<dim3(256, 2), dim3(256), 0, stream>>>(
      outs, outw_bf, outb_bf, d_out, nullptr, 256, 256, 3, 1.0f, query);
}

// Round 6
// 356.270 us; speedup vs baseline: 1.1528x; 1.1528x over previous
//
#include <hip/hip_runtime.h>
#include <hip/hip_bf16.h>
#include <stdint.h>

typedef __bf16 bf16_t;
typedef __bf16 bf16x8 __attribute__((ext_vector_type(8)));
typedef __bf16 bf16x4 __attribute__((ext_vector_type(4)));
typedef float f32x4 __attribute__((ext_vector_type(4)));

// Shapes: B=4 Ng=8192 C=256 H=W=128 Nt=512 M=8 P=4 Ch=32
#define CEXP 0.25506807186679906f  // (1/sqrt(32)) * log2(e), folded into K

__device__ __forceinline__ float ldf(const void* p, size_t i, int isf) {
  return isf ? ((const float*)p)[i] : (float)((const bf16_t*)p)[i];
}

// per-wave dtype detect on query[0:128 elems] — deterministic everywhere
__device__ __forceinline__ int detect_isf(const void* q) {
  const uint16_t* u = (const uint16_t*)q;
  const int lane = threadIdx.x & 63;
  const uint16_t v = u[2 * lane];
  const int e = (v >> 7) & 0xFF;
  const int weird = (e >= 0x86 || (v != 0 && e <= 0x65)) ? 1 : 0;
  return (__popcll(__ballot(weird)) >= 16) ? 1 : 0;
}

__device__ __forceinline__ float fexp2(float x) {
#if __has_builtin(__builtin_amdgcn_exp2f)
  return __builtin_amdgcn_exp2f(x);
#else
  return exp2f(x);
#endif
}

// 16x16x16 bf16 MFMA: C-layout of a 16x16 tile == B-layout of this shape.
__device__ __forceinline__ f32x4 mfma16x16x16(bf16x4 a, bf16x4 b, f32x4 c) {
#if __has_builtin(__builtin_amdgcn_mfma_f32_16x16x16_bf16)
  return __builtin_amdgcn_mfma_f32_16x16x16_bf16(a, b, c, 0, 0, 0);
#else
  typedef short s16x4 __attribute__((ext_vector_type(4)));
  return __builtin_amdgcn_mfma_f32_16x16x16bf16_1k(
      __builtin_bit_cast(s16x4, a), __builtin_bit_cast(s16x4, b), c, 0, 0, 0);
#endif
}

// async global->LDS, 16B per lane
__device__ __forceinline__ void stage16(const bf16_t* g, bf16_t* l) {
  __builtin_amdgcn_global_load_lds((const __attribute__((address_space(1))) void*)g,
                                   (__attribute__((address_space(3))) void*)l, 16, 0, 0);
}

// ====== merged prep: weights->bf16 blob | tf projection | wpad hi/lo =======
__global__ __launch_bounds__(256) void prep_all(
    const void* __restrict__ query,
    const void* in_w, const void* in_b, const void* mow, const void* mob,
    const void* outw, const void* outb,
    const void* trajp, const void* tw, const void* tb,
    const void* offs_w, const void* attw_w, const void* offs_b, const void* attw_b,
    bf16_t* __restrict__ blob, bf16_t* __restrict__ tf,
    bf16_t* __restrict__ Wph, bf16_t* __restrict__ Wpl, bf16_t* __restrict__ bp)
{
  const int isf = detect_isf(query);
  const int bid = blockIdx.x;
  if (bid < 322) {
    const int g = (bid * 256 + threadIdx.x) * 4;
    if (g >= 328960) return;
    const void* src; size_t off;
    if      (g < 196608) { src = in_w; off = g; }
    else if (g < 197376) { src = in_b; off = g - 196608; }
    else if (g < 262912) { src = mow;  off = g - 197376; }
    else if (g < 263168) { src = mob;  off = g - 262912; }
    else if (g < 328704) { src = outw; off = g - 263168; }
    else                 { src = outb; off = g - 328704; }
#pragma unroll
    for (int k = 0; k < 4; k++) blob[g + k] = (bf16_t)ldf(src, off + k, isf);
  } else if (bid < 322 + 2048) {
    const int rowb = bid - 322;
    const int c = threadIdx.x;
    const float x = ldf(trajp, rowb * 2 + 0, isf);
    const float y = ldf(trajp, rowb * 2 + 1, isf);
    const float v = x * ldf(tw, c * 2 + 0, isf) + y * ldf(tw, c * 2 + 1, isf) + ldf(tb, c, isf);
    tf[(size_t)rowb * 256 + c] = (bf16_t)v;
  } else {
    const int idx = (bid - 2370) * 256 + threadIdx.x;
    const int rowp = idx >> 8, c = idx & 255;
    float v = 0.0f;
    if (rowp < 64)      v = ldf(offs_w, rowp * 256 + c, isf);
    else if (rowp < 96) v = ldf(attw_w, (rowp - 64) * 256 + c, isf);
    const bf16_t hi = (bf16_t)v;
    Wph[idx] = hi;
    Wpl[idx] = (bf16_t)(v - (float)hi);
    if (idx < 128) {
      float bv = 0.0f;
      if (idx < 64)      bv = ldf(offs_b, idx, isf);
      else if (idx < 96) bv = ldf(attw_b, idx - 64, isf);
      bp[idx] = (bf16_t)bv;
    }
  }
}

// ============== async-staged bf16 GEMM: C = A@W^T + bias ===================
// mode 0: bf16 store; mode 3: dtype-of-query store; mode 6: K scaled + V transposed
#define TM 128
#define TN 128
#define TKK 64

__global__ __launch_bounds__(256) void gemm_async(
    const bf16_t* __restrict__ A, const bf16_t* __restrict__ W,
    const bf16_t* __restrict__ bias, void* __restrict__ Cout,
    void* __restrict__ Cout2, int Ndim, int Kdim, int mode, float kscale,
    const void* __restrict__ qdet)
{
  __shared__ __align__(16) bf16_t As[TM * TKK];
  __shared__ __align__(16) bf16_t Ws[TN * TKK];
  const int t    = threadIdx.x;
  const int lane = t & 63;
  const int w    = t >> 6;
  const int wm   = (w & 1) * 64;
  const int wn   = (w >> 1) * 64;
  const int q4   = lane >> 4;
  const int r16  = lane & 15;
  const int tm   = blockIdx.x * TM;
  const int tn   = blockIdx.y * TN;

  f32x4 acc[4][4] = {};

  for (int kt = 0; kt < Kdim; kt += TKK) {
    __syncthreads();
#pragma unroll
    for (int r = 0; r < 4; r++) {
      const int L = w * 256 + r * 64 + lane;
      const int R = L >> 3, c = (L & 7) * 8;
      stage16(A + (size_t)(tm + R) * Kdim + kt + c, As + L * 8);
      stage16(W + (size_t)(tn + R) * Kdim + kt + c, Ws + L * 8);
    }
    __syncthreads();
#pragma unroll
    for (int ks = 0; ks < TKK; ks += 32) {
      bf16x8 af[4], bfm[4];
#pragma unroll
      for (int i = 0; i < 4; i++)
        af[i] = *(const bf16x8*)(As + (wm + 16 * i + r16) * TKK + ks + q4 * 8);
#pragma unroll
      for (int j = 0; j < 4; j++)
        bfm[j] = *(const bf16x8*)(Ws + (wn + 16 * j + r16) * TKK + ks + q4 * 8);
#pragma unroll
      for (int i = 0; i < 4; i++)
#pragma unroll
        for (int j = 0; j < 4; j++)
          acc[i][j] = __builtin_amdgcn_mfma_f32_16x16x32_bf16(af[i], bfm[j], acc[i][j], 0, 0, 0);
    }
  }

  const int isf = (mode == 3) ? detect_isf(qdet) : 1;
#pragma unroll
  for (int j = 0; j < 4; j++) {
    const int col = tn + wn + 16 * j + r16;
    const float bv = (float)bias[col];
#pragma unroll
    for (int i = 0; i < 4; i++) {
      const int row0 = tm + wm + 16 * i + q4 * 4;
#pragma unroll
      for (int rr = 0; rr < 4; rr++) {
        const float v = acc[i][j][rr] + bv;
        const size_t off = (size_t)(row0 + rr) * Ndim + col;
        if (mode == 0) {
          ((bf16_t*)Cout)[off] = (bf16_t)v;
        } else if (mode == 6) {
          const int rowg = row0 + rr;
          if (col < 256) {
            ((bf16_t*)Cout)[(size_t)rowg * 256 + col] = (bf16_t)(v * kscale);
          } else {
            const int bb = rowg >> 9, tt = rowg & 511;
            const int c2 = col - 256;
            const int mm = c2 >> 5, ch = c2 & 31;
            ((bf16_t*)Cout2)[(((size_t)(bb * 8 + mm) * 32 + ch) << 9) + tt] = (bf16_t)v;
          }
        } else {
          if (isf) ((float*)Cout)[off] = v; else ((bf16_t*)Cout)[off] = (bf16_t)v;
        }
      }
    }
  }
}

// ============== VGPR-staged GEMM with dtype-flex A (Q-proj) ================
__global__ __launch_bounds__(256) void gemm_f32a(
    const void* __restrict__ Araw, const bf16_t* __restrict__ W,
    const bf16_t* __restrict__ bias, bf16_t* __restrict__ Cout,
    int Ndim, int Kdim, const void* __restrict__ qdet)
{
  __shared__ __align__(16) bf16_t As[TM * TKK];
  __shared__ __align__(16) bf16_t Ws[TN * TKK];
  const int t    = threadIdx.x;
  const int lane = t & 63;
  const int w    = t >> 6;
  const int wm   = (w & 1) * 64;
  const int wn   = (w >> 1) * 64;
  const int q4   = lane >> 4;
  const int r16  = lane & 15;
  const int tm   = blockIdx.x * TM;
  const int tn   = blockIdx.y * TN;
  const int aisf = detect_isf(qdet);

  f32x4 acc[4][4] = {};
  const int srow = t >> 1;
  const int skb  = (t & 1) * 32;

  for (int kt = 0; kt < Kdim; kt += TKK) {
    __syncthreads();
    if (aisf) {
      const float4* ga = (const float4*)((const float*)Araw + (size_t)(tm + srow) * Kdim + kt + skb);
#pragma unroll
      for (int kk = 0; kk < 8; kk++) {
        const float4 u = ga[kk];
        bf16x4 h = {(bf16_t)u.x, (bf16_t)u.y, (bf16_t)u.z, (bf16_t)u.w};
        *(bf16x4*)(As + srow * TKK + skb + kk * 4) = h;
      }
    } else {
      const uint4* ga = (const uint4*)((const bf16_t*)Araw + (size_t)(tm + srow) * Kdim + kt + skb);
      uint4* la = (uint4*)(As + srow * TKK + skb);
      la[0] = ga[0]; la[1] = ga[1]; la[2] = ga[2]; la[3] = ga[3];
    }
    {
      const uint4* gw = (const uint4*)(W + (size_t)(tn + srow) * Kdim + kt + skb);
      uint4* lw = (uint4*)(Ws + srow * TKK + skb);
      lw[0] = gw[0]; lw[1] = gw[1]; lw[2] = gw[2]; lw[3] = gw[3];
    }
    __syncthreads();
#pragma unroll
    for (int ks = 0; ks < TKK; ks += 32) {
      bf16x8 af[4], bfm[4];
#pragma unroll
      for (int i = 0; i < 4; i++)
        af[i] = *(const bf16x8*)(As + (wm + 16 * i + r16) * TKK + ks + q4 * 8);
#pragma unroll
      for (int j = 0; j < 4; j++)
        bfm[j] = *(const bf16x8*)(Ws + (wn + 16 * j + r16) * TKK + ks + q4 * 8);
#pragma unroll
      for (int i = 0; i < 4; i++)
#pragma unroll
        for (int j = 0; j < 4; j++)
          acc[i][j] = __builtin_amdgcn_mfma_f32_16x16x32_bf16(af[i], bfm[j], acc[i][j], 0, 0, 0);
    }
  }

#pragma unroll
  for (int j = 0; j < 4; j++) {
    const int col = tn + wn + 16 * j + r16;
    const float bv = (float)bias[col];
#pragma unroll
    for (int i = 0; i < 4; i++) {
      const int row0 = tm + wm + 16 * i + q4 * 4;
#pragma unroll
      for (int rr = 0; rr < 4; rr++)
        Cout[(size_t)(row0 + rr) * Ndim + col] = (bf16_t)(acc[i][j][rr] + bv);
    }
  }
}

// ==================== attention: LDS-free, per-head ========================
// K pre-scaled by CEXP. S^T = K·Q^T; p = exp2(s); O^T = V^T·P^T.
// grid (Ng/512, B*M); wave owns 128 q-rows (8 q-tiles) -> 8x arithmetic per
// K/V load; register prefetch-by-1 covers L2 latency.
__global__ __launch_bounds__(256, 2) void attn_kernel(
    const bf16_t* __restrict__ Q, const bf16_t* __restrict__ Kk,
    const bf16_t* __restrict__ Vt, bf16_t* __restrict__ ctx)
{
  const int t = threadIdx.x;
  const int lane = t & 63, w = t >> 6;
  const int q4 = lane >> 4, r16 = lane & 15;
  const int bm = blockIdx.y;
  const int b = bm >> 3, m = bm & 7;
  const int q0 = blockIdx.x * 512 + w * 128;

  bf16x8 qf[8];
#pragma unroll
  for (int qt = 0; qt < 8; qt++)
    qf[qt] = *(const bf16x8*)(Q + ((size_t)(b * 8192 + q0 + qt * 16 + r16) * 256 + m * 32 + q4 * 8));

  f32x4 acc[8][2] = {};
  float lsum[8] = {0.f, 0.f, 0.f, 0.f, 0.f, 0.f, 0.f, 0.f};

  const bf16_t* kbase  = Kk + (size_t)b * 512 * 256 + m * 32 + (size_t)r16 * 256 + q4 * 8;
  const bf16_t* vbase0 = Vt + (size_t)bm * 32 * 512 + ((size_t)r16 << 9) + q4 * 4;
  const bf16_t* vbase1 = vbase0 + (16 << 9);

  bf16x8 kf = *(const bf16x8*)(kbase);
  bf16x4 v0 = *(const bf16x4*)(vbase0);
  bf16x4 v1 = *(const bf16x4*)(vbase1);

  for (int k0 = 0; k0 < 512; k0 += 16) {
    // prefetch next tile (last iter over-reads into adjacent ws region — safe,
    // value never consumed)
    const int nxt = k0 + 16;
    const bf16x8 kf_n = *(const bf16x8*)(kbase + (size_t)nxt * 256);
    const bf16x4 v0_n = *(const bf16x4*)(vbase0 + nxt);
    const bf16x4 v1_n = *(const bf16x4*)(vbase1 + nxt);
#pragma unroll
    for (int qt = 0; qt < 8; qt++) {
      f32x4 z = {};
      const f32x4 s = __builtin_amdgcn_mfma_f32_16x16x32_bf16(kf, qf[qt], z, 0, 0, 0);
      union { float f; uint32_t u; } a0, a1, a2, a3;
      a0.f = fexp2(s[0]); a1.f = fexp2(s[1]); a2.f = fexp2(s[2]); a3.f = fexp2(s[3]);
      lsum[qt] += (a0.f + a1.f) + (a2.f + a3.f);
      uint2 rp;
      rp.x = __builtin_amdgcn_perm(a1.u + 0x8000u, a0.u + 0x8000u, 0x07060302u);
      rp.y = __builtin_amdgcn_perm(a3.u + 0x8000u, a2.u + 0x8000u, 0x07060302u);
      const bf16x4 p = __builtin_bit_cast(bf16x4, rp);
      acc[qt][0] = mfma16x16x16(v0, p, acc[qt][0]);
      acc[qt][1] = mfma16x16x16(v1, p, acc[qt][1]);
    }
    kf = kf_n; v0 = v0_n; v1 = v1_n;
  }

#pragma unroll
  for (int qt = 0; qt < 8; qt++) {
    float v = lsum[qt];
    v += __shfl_xor(v, 16, 64);
    v += __shfl_xor(v, 32, 64);
    const float inv = 1.0f / v;
    const size_t row = (size_t)b * 8192 + q0 + qt * 16 + r16;
    bf16x4 o0, o1;
#pragma unroll
    for (int rr = 0; rr < 4; rr++) {
      o0[rr] = (bf16_t)(acc[qt][0][rr] * inv);
      o1[rr] = (bf16_t)(acc[qt][1][rr] * inv);
    }
    *(bf16x4*)(ctx + row * 256 + m * 32 + q4 * 4)      = o0;
    *(bf16x4*)(ctx + row * 256 + m * 32 + 16 + q4 * 4) = o1;
  }
}

// ================= residual + LayerNorm -> gq hi/lo split ==================
__global__ __launch_bounds__(256) void ln_kernel(
    const bf16_t* __restrict__ y2, const void* __restrict__ query,
    const void* __restrict__ g, const void* __restrict__ beta,
    bf16_t* __restrict__ gqh, bf16_t* __restrict__ gql)
{
  const int isf = detect_isf(query);
  const int rowb = blockIdx.x * 4 + (threadIdx.x >> 6);
  const int lane = threadIdx.x & 63;
  const size_t base = (size_t)rowb * 256;
  float x[4];
  float s = 0.f;
#pragma unroll
  for (int k = 0; k < 4; k++) {
    const int c = lane + 64 * k;
    x[k] = ldf(query, base + c, isf) + (float)y2[base + c];
    s += x[k];
  }
  for (int d = 1; d < 64; d <<= 1) s += __shfl_xor(s, d, 64);
  const float mu = s * (1.0f / 256.0f);
  float vs = 0.f;
#pragma unroll
  for (int k = 0; k < 4; k++) { const float d = x[k] - mu; vs += d * d; }
  for (int d = 1; d < 64; d <<= 1) vs += __shfl_xor(vs, d, 64);
  const float rstd = rsqrtf(vs * (1.0f / 256.0f) + 1e-5f);
#pragma unroll
  for (int k = 0; k < 4; k++) {
    const int c = lane + 64 * k;
    const float gv = (x[k] - mu) * rstd * ldf(g, c, isf) + ldf(beta, c, isf);
    const bf16_t hi = (bf16_t)gv;
    gqh[base + c] = hi;
    gql[base + c] = (bf16_t)(gv - (float)hi);
  }
}

// ===== fused offs/attw GEMM: ysamp = gqh*(Wh+Wl)^T + gql*Wh^T + bias =======
__global__ __launch_bounds__(256) void gemm_offs(
    const bf16_t* __restrict__ Ahg, const bf16_t* __restrict__ Alg,
    const bf16_t* __restrict__ Whg, const bf16_t* __restrict__ Wlg,
    const bf16_t* __restrict__ bias, float* __restrict__ Cout)
{
  __shared__ __align__(16) bf16_t Ah[128 * 64];
  __shared__ __align__(16) bf16_t Al[128 * 64];
  __shared__ __align__(16) bf16_t Wh[128 * 64];
  __shared__ __align__(16) bf16_t Wl[128 * 64];
  const int t    = threadIdx.x;
  const int lane = t & 63;
  const int w    = t >> 6;
  const int wm   = (w & 1) * 64;
  const int wn   = (w >> 1) * 64;
  const int q4   = lane >> 4;
  const int r16  = lane & 15;
  const int tm   = blockIdx.x * 128;

  f32x4 acc[4][4] = {};
  const int srow = t >> 1;
  const int skb  = (t & 1) * 32;

  for (int kt = 0; kt < 256; kt += 64) {
    __syncthreads();
    {
      const uint4* g0 = (const uint4*)(Ahg + (size_t)(tm + srow) * 256 + kt + skb);
      uint4* l0 = (uint4*)(Ah + srow * 64 + skb);
      l0[0] = g0[0]; l0[1] = g0[1]; l0[2] = g0[2]; l0[3] = g0[3];
      const uint4* g1 = (const uint4*)(Alg + (size_t)(tm + srow) * 256 + kt + skb);
      uint4* l1 = (uint4*)(Al + srow * 64 + skb);
      l1[0] = g1[0]; l1[1] = g1[1]; l1[2] = g1[2]; l1[3] = g1[3];
      const uint4* g2 = (const uint4*)(Whg + (size_t)srow * 256 + kt + skb);
      uint4* l2 = (uint4*)(Wh + srow * 64 + skb);
      l2[0] = g2[0]; l2[1] = g2[1]; l2[2] = g2[2]; l2[3] = g2[3];
      const uint4* g3 = (const uint4*)(Wlg + (size_t)srow * 256 + kt + skb);
      uint4* l3 = (uint4*)(Wl + srow * 64 + skb);
      l3[0] = g3[0]; l3[1] = g3[1]; l3[2] = g3[2]; l3[3] = g3[3];
    }
    __syncthreads();
#pragma unroll
    for (int ks = 0; ks < 64; ks += 32) {
      bf16x8 ah[4], al[4], bh[4], bl[4];
#pragma unroll
      for (int i = 0; i < 4; i++) {
        ah[i] = *(const bf16x8*)(Ah + (wm + 16 * i + r16) * 64 + ks + q4 * 8);
        al[i] = *(const bf16x8*)(Al + (wm + 16 * i + r16) * 64 + ks + q4 * 8);
      }
#pragma unroll
      for (int j = 0; j < 4; j++) {
        bh[j] = *(const bf16x8*)(Wh + (wn + 16 * j + r16) * 64 + ks + q4 * 8);
        bl[j] = *(const bf16x8*)(Wl + (wn + 16 * j + r16) * 64 + ks + q4 * 8);
      }
#pragma unroll
      for (int i = 0; i < 4; i++)
#pragma unroll
        for (int j = 0; j < 4; j++) {
          f32x4 a = acc[i][j];
          a = __builtin_amdgcn_mfma_f32_16x16x32_bf16(al[i], bh[j], a, 0, 0, 0);
          a = __builtin_amdgcn_mfma_f32_16x16x32_bf16(ah[i], bl[j], a, 0, 0, 0);
          a = __builtin_amdgcn_mfma_f32_16x16x32_bf16(ah[i], bh[j], a, 0, 0, 0);
          acc[i][j] = a;
        }
    }
  }

#pragma unroll
  for (int j = 0; j < 4; j++) {
    const int col = wn + 16 * j + r16;
    const float bv = (float)bias[col];
#pragma unroll
    for (int i = 0; i < 4; i++) {
      const int row0 = tm + wm + 16 * i + q4 * 4;
#pragma unroll
      for (int rr = 0; rr < 4; rr++)
        Cout[(size_t)(row0 + rr) * 128 + col] = acc[i][j][rr] + bv;
    }
  }
}

// ============ value transpose (B,C,H,W) -> (B,M,H,W,Ch) bf16 ===============
__global__ __launch_bounds__(256) void transpose_value(
    const void* __restrict__ V, bf16_t* __restrict__ Vp, const void* __restrict__ qdet)
{
  __shared__ bf16_t tile[32][130];
  const int isf = detect_isf(qdet);
  const int bid = blockIdx.x;
  const int h = bid & 127;
  const int bm = bid >> 7;
  const int b = bm >> 3, mm = bm & 7;
  const int t = threadIdx.x;
  for (int idx = t; idx < 32 * 128; idx += 256) {
    const int ch = idx >> 7, ww = idx & 127;
    tile[ch][ww] = (bf16_t)ldf(V, (((size_t)b * 256 + mm * 32 + ch) * 128 + h) * 128 + ww, isf);
  }
  __syncthreads();
  const size_t base = ((size_t)bm * 128 + h) * 4096;
  for (int idx = t; idx < 32 * 128; idx += 256) {
    const int ww = idx >> 5, ch = idx & 31;
    Vp[base + idx] = tile[ch][ww];
  }
}

// ===================== deformable bilinear sampler =========================
__global__ __launch_bounds__(256) void sampler(
    const float* __restrict__ ys, const void* __restrict__ refp,
    const bf16_t* __restrict__ vperm, bf16_t* __restrict__ outs,
    const void* __restrict__ qdet)
{
  const int isf = detect_isf(qdet);
  const int t = threadIdx.x;
  const int qt = blockIdx.x;
  const int bm = blockIdx.y;
  const int b = bm >> 3, m = bm & 7;
  const int qq = qt * 256 + t;
  const size_t row = (size_t)b * 8192 + qq;
  const float* y = ys + row * 128;
  const float rx = ldf(refp, row * 2 + 0, isf);
  const float ry = ldf(refp, row * 2 + 1, isf);

  const float l0 = y[64 + m * 4 + 0], l1 = y[64 + m * 4 + 1];
  const float l2 = y[64 + m * 4 + 2], l3 = y[64 + m * 4 + 3];
  const float mx = fmaxf(fmaxf(l0, l1), fmaxf(l2, l3));
  const float e0 = __expf(l0 - mx), e1 = __expf(l1 - mx);
  const float e2 = __expf(l2 - mx), e3 = __expf(l3 - mx);
  const float inv = 1.0f / (e0 + e1 + e2 + e3);
  const float aw[4] = {e0 * inv, e1 * inv, e2 * inv, e3 * inv};

  float acc[32];
#pragma unroll
  for (int ch = 0; ch < 32; ch++) acc[ch] = 0.0f;

  const bf16_t* vbase = vperm + (size_t)bm * (128 * 128 * 32);

  for (int p = 0; p < 4; p++) {
    const float gx = (rx + y[m * 8 + p * 2 + 0]) * 128.0f - 0.5f;
    const float gy = (ry + y[m * 8 + p * 2 + 1]) * 128.0f - 0.5f;
    const float x0f = floorf(gx), y0f = floorf(gy);
    const int x0 = (int)x0f, y0i = (int)y0f;
    const float wx1 = gx - x0f, wx0 = 1.0f - wx1;
    const float wy1 = gy - y0f, wy0 = 1.0f - wy1;
    const float a = aw[p];
    for (int cy = 0; cy < 2; cy++) {
      const int yy = y0i + cy;
      if (yy < 0 || yy >= 128) continue;
      const float wy = cy ? wy1 : wy0;
      for (int cx = 0; cx < 2; cx++) {
        const int xx = x0 + cx;
        if (xx < 0 || xx >= 128) continue;
        const float wgt = a * wy * (cx ? wx1 : wx0);
        const bf16x8* src8 = (const bf16x8*)(vbase + ((size_t)yy * 128 + xx) * 32);
#pragma unroll
        for (int vv = 0; vv < 4; vv++) {
          const bf16x8 d = src8[vv];
#pragma unroll
          for (int e = 0; e < 8; e++) acc[vv * 8 + e] += wgt * (float)d[e];
        }
      }
    }
  }

  const size_t obase = (size_t)b * 8192;
#pragma unroll
  for (int ch = 0; ch < 32; ch++) {
    const size_t orow = obase + (size_t)(ch * 8 + m) * 32 + qt;
    outs[orow * 256 + t] = (bf16_t)acc[ch];
  }
}

// ===========================================================================
extern "C" void kernel_launch(void* const* d_in, const int* in_sizes, int n_in,
                              void* d_out, int out_size, void* d_ws, size_t ws_size,
                              hipStream_t stream) {
  const void* query = d_in[0];
  const void* value = d_in[1];
  const void* refp  = d_in[2];
  const void* trajp = d_in[3];
  const void* in_w  = d_in[4];
  const void* in_b  = d_in[5];
  const void* mow   = d_in[6];
  const void* mob   = d_in[7];
  const void* lng   = d_in[8];
  const void* lnb   = d_in[9];
  const void* tw    = d_in[10];
  const void* tb    = d_in[11];
  const void* ow    = d_in[12];
  const void* ob    = d_in[13];
  const void* aww   = d_in[14];
  const void* awb   = d_in[15];
  const void* outw  = d_in[16];
  const void* outb  = d_in[17];

  char* base = (char*)d_ws;
  float*  ysamp = (float*)(base);
  bf16_t* qout  = (bf16_t*)(base + 16777216);
  bf16_t* ctx   = (bf16_t*)(base + 33554432);
  bf16_t* y2    = (bf16_t*)(base + 50331648);
  bf16_t* tf_ws = (bf16_t*)(base + 67108864);
  bf16_t* k_ws  = (bf16_t*)(base + 68157440);
  bf16_t* vt_g  = (bf16_t*)(base + 69206016);
  bf16_t* blob  = (bf16_t*)(base + 70254592);

  bf16_t* gqh   = qout;
  bf16_t* gql   = ctx;
  bf16_t* vperm = (bf16_t*)(base + 16777216);   // 32MB, alias R1+R2
  bf16_t* outs  = y2;

  bf16_t* inw_bf  = blob;
  bf16_t* inb_bf  = blob + 196608;
  bf16_t* mow_bf  = blob + 197376;
  bf16_t* mob_bf  = blob + 262912;
  bf16_t* outw_bf = blob + 263168;
  bf16_t* outb_bf = blob + 328704;
  bf16_t* wph     = blob + 328960;
  bf16_t* wpl     = blob + 361728;
  bf16_t* bpad    = blob + 394496;

  prep_all<<<dim3(2498), dim3(256), 0, stream>>>(
      query, in_w, in_b, mow, mob, outw, outb, trajp, tw, tb,
      ow, aww, ob, awb, blob, tf_ws, wph, wpl, bpad);
  gemm_async<<<dim3(16, 4), dim3(256), 0, stream>>>(
      tf_ws, inw_bf + 65536, inb_bf + 256, (void*)k_ws, (void*)vt_g, 512, 256, 6, CEXP, query);
  gemm_f32a<<<dim3(256, 2), dim3(256), 0, stream>>>(
      query, inw_bf, inb_bf, qout, 256, 256, query);
  attn_kernel<<<dim3(16, 32), dim3(256), 0, stream>>>(qout, k_ws, vt_g, ctx);
  gemm_async<<<dim3(256, 2), dim3(256), 0, stream>>>(
      ctx, mow_bf, mob_bf, (void*)y2, nullptr, 256, 256, 0, 1.0f, query);
  ln_kernel<<<dim3(8192), dim3(256), 0, stream>>>(y2, query, lng, lnb, gqh, gql);
  gemm_offs<<<dim3(256, 1), dim3(256), 0, stream>>>(gqh, gql, wph, wpl, bpad, ysamp);
  transpose_value<<<dim3(4096), dim3(256), 0, stream>>>(value, vperm, query);
  sampler<<<dim3(32, 32), dim3(256), 0, stream>>>(ysamp, refp, vperm, outs, query);
  gemm_async<<<dim3(256, 2), dim3(256), 0, stream>>>(
      outs, outw_bf, outb_bf, d_out, nullptr, 256, 256, 3, 1.0f, query);
}